// Round 3
// baseline (480.431 us; speedup 1.0000x reference)
//
#include <hip/hip_runtime.h>

#define TT 512
#define BB 256
#define DD 128
#define HH 128
#define QQ 8

struct Params {
    const float* x;
    const float* W[4];
    const float* b[4];
    const float* th[4];
    const float* U[4];
    const float* cb[4];
    const float* zx;     // precomputed x-half of z: [TT][BB][32], col = g*8+q
    float* out;
};

struct GParams {
    const float* x;
    const float* W[4];
    float* zx;
};

__device__ __forceinline__ float rcp_f(float x)  { return __builtin_amdgcn_rcpf(x); }
__device__ __forceinline__ float exp2_f(float x) { return __builtin_amdgcn_exp2f(x); }

template<int CTRL>
__device__ __forceinline__ float dpp_mov(float x) {
    int r = __builtin_amdgcn_update_dpp(0, __float_as_int(x), CTRL, 0xF, 0xF, true);
    return __int_as_float(r);
}
template<int CTRL, int RM>
__device__ __forceinline__ float dpp_mul1(float x) {
    int r = __builtin_amdgcn_update_dpp(0x3f800000 /*1.0f*/, __float_as_int(x),
                                        CTRL, RM, 0xF, false);
    return __int_as_float(r);
}
#define RDLANE(v, l) __int_as_float(__builtin_amdgcn_readlane(__float_as_int(v), (l)))

__device__ __forceinline__ void bar_lds() {
    asm volatile("s_waitcnt lgkmcnt(0)\n\ts_barrier" ::: "memory");
}

// ---------------------------------------------------------------------------
// Kernel 1: zx GEMM. ZX[t][b][g*8+q] = sum_d W[g][q][d] * x[t][b][d], d<128.
// One wave per (t, 32-b strip); lane = (gq, half): 64-elem half-dot in regs,
// pair-reduce via DPP xor1, even lanes store 32 contiguous floats.
// ---------------------------------------------------------------------------
__global__ __launch_bounds__(256, 1) void zxgemm(GParams g) {
    const int tid = threadIdx.x;
    const int l   = tid & 63;
    const int wv  = tid >> 6;
    const int gw  = blockIdx.x * 4 + wv;     // global wave id, [0, T*B/32)
    const int t   = gw >> 3;
    const int b0  = (gw & 7) * 32;
    const int gq  = l >> 1;                  // 0..31  (gate = gq>>3, qubit = gq&7)
    const int half = l & 1;

    // W x-half slice for this (gq, half): 64 floats in regs
    const float* Wp = g.W[gq >> 3] + (gq & 7) * (DD + HH) + half * 64;
    float4 w4[16];
    #pragma unroll
    for (int j = 0; j < 16; ++j) w4[j] = *(const float4*)(Wp + 4 * j);

    float* zrow = g.zx + ((size_t)t * BB + b0) * 32 + gq;
    const float* xbase = g.x + ((size_t)t * BB + b0) * DD + half * 64;

    for (int bb = 0; bb < 32; ++bb) {
        const float* xp = xbase + (size_t)bb * DD;
        float a0 = 0.f, a1 = 0.f, a2 = 0.f, a3 = 0.f;
        #pragma unroll
        for (int j = 0; j < 16; ++j) {
            float4 v = *(const float4*)(xp + 4 * j);
            a0 = fmaf(w4[j].x, v.x, a0);
            a1 = fmaf(w4[j].y, v.y, a1);
            a2 = fmaf(w4[j].z, v.z, a2);
            a3 = fmaf(w4[j].w, v.w, a3);
        }
        float s = (a0 + a1) + (a2 + a3);
        s += dpp_mov<0xB1>(s);               // pair sum (xor1): even lane holds full dot
        if (half == 0) zrow[(size_t)bb * 32] = s;
    }
}

// ---------------------------------------------------------------------------
// Kernel 2 (slim): recurrence with zx precomputed. 2-barrier split:
// phase A (all waves: zh dot + qgate + Uexp) | bar | phase B (waves 0-1: E;
// wave 2: zx chunk staging global->reg->LDS; wave 3: idle) | bar.
// vs R2: removes Wx, xbuf, x staging, in-loop zx dot (16 b128 LDS reads/step
// = ~200cy of LDS-pipe occupancy) -> shorter barrier-2 laggard + less LDS
// contention on the critical path.
// ---------------------------------------------------------------------------
__global__ __launch_bounds__(256, 1) void qlstm(Params p) {
    __shared__ __align__(16) float hbuf[144];       // h_{t-1} (padded)
    __shared__ float pre[512];                      // gate preactivations (scaled)
    __shared__ __align__(16) float zxw[2][8][32];   // staged zx chunks (8 steps)

    const int tid = threadIdx.x;
    const int bId = blockIdx.x;
    const int ln  = tid & 63;
    const int wv  = tid >> 6;        // wave id == gate id
    const int qub = ln >> 3;         // qubit (octet)
    const int part8 = ln & 7;        // 16-float h-slice

    // ---- zh weights: W[wv][qub][128 + 16*part8 + j] ----
    float Wh[16];
    {
        const float* Wg = p.W[wv] + qub * (DD + HH) + DD + part8 * 16;
        #pragma unroll
        for (int j = 0; j < 16; ++j) Wh[j] = Wg[j];
    }
    const float breg = p.b[wv][qub] + p.th[wv][qub];  // fused bias+theta

    // ---- U expansion constants, pre-scaled for exp2-based activations ----
    const float esc = (wv == 2) ? 2.885390081777927f : -1.442695040888963f;
    float Ua[8], Ub[8];
    #pragma unroll
    for (int j = 0; j < 8; ++j) {
        Ua[j] = p.U[wv][ln * QQ + j] * esc;
        Ub[j] = p.U[wv][(ln + 64) * QQ + j] * esc;
    }
    const float cba = p.cb[wv][ln] * esc;
    const float cbb = p.cb[wv][ln + 64] * esc;

    float cst = 0.f;
    float hn_last = 0.f;

    if (tid < 128) hbuf[tid + 4 * (tid >> 5)] = 0.f;

    // ---- zx staging geometry (wave 2): lane l covers step 8*tch+(l>>3), cols (l&7)*4.. ----
    const int zst = ln >> 3;                 // step within chunk
    const int zc  = (ln & 7) * 4;            // col base
    float4 zr = make_float4(0.f, 0.f, 0.f, 0.f);
    if (wv == 2) {   // chunk 0, synchronous
        float4 v = *(const float4*)(p.zx + ((size_t)zst * BB + bId) * 32 + zc);
        *(float4*)&zxw[0][zst][zc] = v;
    }
    __syncthreads();

    const float* hsrc = &hbuf[16 * part8 + 4 * (part8 >> 1)];
    const size_t orow_step = (size_t)BB * HH;
    size_t orow = (size_t)bId * HH + tid;     // used by tid<128 only

    #pragma unroll 8
    for (int t = 0; t < TT; ++t) {
        // ---- Z: issue LDS reads first (zxs + 4x b128 h), stream the pipe ----
        const float zxs = zxw[(t >> 3) & 1][t & 7][8 * wv + qub];  // octet broadcast
        const float4 h0 = ((const float4*)hsrc)[0];
        const float4 h1 = *(const float4*)(hsrc + 4);
        const float4 h2 = *(const float4*)(hsrc + 8);
        const float4 h3 = *(const float4*)(hsrc + 12);

        float a0 = Wh[0] * h0.x, a1 = Wh[1] * h0.y, a2 = Wh[2] * h0.z, a3 = Wh[3] * h0.w;
        a0 = fmaf(Wh[4],  h1.x, a0); a1 = fmaf(Wh[5],  h1.y, a1);
        a2 = fmaf(Wh[6],  h1.z, a2); a3 = fmaf(Wh[7],  h1.w, a3);
        a0 = fmaf(Wh[8],  h2.x, a0); a1 = fmaf(Wh[9],  h2.y, a1);
        a2 = fmaf(Wh[10], h2.z, a2); a3 = fmaf(Wh[11], h2.w, a3);
        a0 = fmaf(Wh[12], h3.x, a0); a1 = fmaf(Wh[13], h3.y, a1);
        a2 = fmaf(Wh[14], h3.z, a2); a3 = fmaf(Wh[15], h3.w, a3);
        float acc = (a0 + a1) + (a2 + a3);
        acc += dpp_mov<0xB1>(acc);
        acc += dpp_mov<0x4E>(acc);
        acc += dpp_mov<0x141>(acc);
        acc += zxs + breg;

        // ---- Qgate: cos + dual stride-8 product scan (DPP) + readlane bcast ----
        const float cv = __cosf(acc);
        float v = cv;
        v *= dpp_mul1<0x118, 0xF>(v);           // row_shr:8
        v *= dpp_mul1<0x142, 0xA>(v);           // row_bcast15 -> rows 1,3
        v *= dpp_mul1<0x143, 0xC>(v);           // row_bcast31 -> rows 2,3
        float u = (ln < 8) ? 1.f : cv;
        u *= dpp_mul1<0x118, 0xF>(u);
        u *= dpp_mul1<0x142, 0xA>(u);
        u *= dpp_mul1<0x143, 0xC>(u);
        const float q0 = RDLANE(u, 63);
        const float q1 = RDLANE(v, 8);
        const float q2 = RDLANE(v, 16);
        const float q3 = RDLANE(v, 24);
        const float q4 = RDLANE(v, 32);
        const float q5 = RDLANE(v, 40);
        const float q6 = RDLANE(v, 48);
        const float q7 = RDLANE(v, 56);

        // ---- U expansion (scaled), tree form ----
        float a01 = fmaf(Ua[1], q1, Ua[0] * q0);
        float b01 = fmaf(Ub[1], q1, Ub[0] * q0);
        float a23 = fmaf(Ua[3], q3, Ua[2] * q2);
        float b23 = fmaf(Ub[3], q3, Ub[2] * q2);
        float a45 = fmaf(Ua[5], q5, Ua[4] * q4);
        float b45 = fmaf(Ub[5], q5, Ub[4] * q4);
        float a67 = fmaf(Ua[7], q7, Ua[6] * q6);
        float b67 = fmaf(Ub[7], q7, Ub[6] * q6);
        float pa = ((a01 + a23) + (a45 + a67)) + cba;
        float pb = ((b01 + b23) + (b45 + b67)) + cbb;
        pre[wv * 128 + ln]      = pa;
        pre[wv * 128 + 64 + ln] = pb;

        bar_lds();   // barrier 1: pre[] visible

        // ---- phase B: E (waves 0-1) | zx staging (wave 2) | idle (wave 3) ----
        if (tid < 128) {
            float p_f = (wv == 0) ? pa : pre[tid];
            float p_i = (wv == 1) ? pb : pre[128 + tid];
            float p_g = pre[256 + tid];
            float p_o = pre[384 + tid];
            float fg = rcp_f(1.f + exp2_f(p_f));
            float ig = rcp_f(1.f + exp2_f(p_i));
            float gg = fmaf(-2.f, rcp_f(1.f + exp2_f(p_g)), 1.f);
            float og = rcp_f(1.f + exp2_f(p_o));
            cst = fmaf(fg, cst, ig * gg);
            float tc = fmaf(-2.f, rcp_f(1.f + exp2_f(cst * 2.885390081777927f)), 1.f);
            float hn = og * tc;
            hn_last = hn;
            hbuf[tid + 4 * (tid >> 5)] = hn;
            p.out[orow] = hn;                    // issue-only
            orow += orow_step;
        } else if (wv == 2) {
            if ((t & 7) == 0) {                  // issue next chunk's global load
                const int tch = (t >> 3) + 1;
                if (tch < TT / 8) {
                    const int s = tch * 8 + zst;
                    zr = *(const float4*)(p.zx + ((size_t)s * BB + bId) * 32 + zc);
                }
            }
            if ((t & 7) == 6) {                  // land it in LDS (other buffer)
                const int tch = (t >> 3) + 1;
                if (tch < TT / 8) {
                    *(float4*)&zxw[tch & 1][zst][zc] = zr;
                }
            }
        }
        bar_lds();   // barrier 2: hbuf / zxw ready for next step
    }

    // ---- tail: hx, cx ----
    if (tid < 128) {
        p.out[(size_t)TT * BB * HH + (size_t)bId * HH + tid] = hn_last;
        p.out[(size_t)TT * BB * HH + (size_t)BB * HH + (size_t)bId * HH + tid] = cst;
    }
}

// ---------------------------------------------------------------------------
// Fallback (R2 kernel, verbatim): used when d_ws is too small for ZX.
// ---------------------------------------------------------------------------
__global__ __launch_bounds__(256, 1) void qlstm_fb(Params p) {
    __shared__ __align__(16) float xbuf[2][8][144];
    __shared__ __align__(16) float hbuf[144];
    __shared__ float pre[512];
    __shared__ float zxbuf[2][32];

    const int tid = threadIdx.x;
    const int bId = blockIdx.x;
    const int ln  = tid & 63;
    const int wv  = tid >> 6;
    const int qub = ln >> 3;
    const int part8 = ln & 7;

    float Wh[16];
    {
        const float* Wg = p.W[wv] + qub * (DD + HH) + DD + part8 * 16;
        #pragma unroll
        for (int j = 0; j < 16; ++j) Wh[j] = Wg[j];
    }
    const float breg = p.b[wv][qub] + p.th[wv][qub];

    const int gz = 2 * (wv - 2) + (ln >> 5);
    const int qz = (ln >> 2) & 7;
    const int pz = ln & 3;
    float Wx[32];
    if (wv >= 2) {
        const float* Wg = p.W[gz] + qz * (DD + HH) + pz * 32;
        #pragma unroll
        for (int j = 0; j < 32; ++j) Wx[j] = Wg[j];
    }

    const float esc = (wv == 2) ? 2.885390081777927f : -1.442695040888963f;
    float Ua[8], Ub[8];
    #pragma unroll
    for (int j = 0; j < 8; ++j) {
        Ua[j] = p.U[wv][ln * QQ + j] * esc;
        Ub[j] = p.U[wv][(ln + 64) * QQ + j] * esc;
    }
    const float cba = p.cb[wv][ln] * esc;
    const float cbb = p.cb[wv][ln + 64] * esc;

    float cst = 0.f;
    float hn_last = 0.f;

    if (tid < 128) hbuf[tid + 4 * (tid >> 5)] = 0.f;

    const int xc_col  = (ln & 31) * 4;
    const int xc_half = ln >> 5;
    const int xc_slot = xc_col + 4 * (xc_col >> 5);
    float4 xr[4];
    #pragma unroll
    for (int j = 0; j < 4; ++j) xr[j] = make_float4(0.f, 0.f, 0.f, 0.f);

    if (wv == 3) {
        #pragma unroll
        for (int j = 0; j < 4; ++j) {
            const int row = 2 * j + xc_half;
            float4 v = *(const float4*)(p.x + ((size_t)row * BB + bId) * DD + xc_col);
            *(float4*)&xbuf[0][row][xc_slot] = v;
        }
    }
    __syncthreads();

    if (wv >= 2) {
        const float* xrow = &xbuf[0][0][36 * pz];
        float b0 = 0.f, b1 = 0.f, b2 = 0.f, b3 = 0.f;
        #pragma unroll
        for (int i = 0; i < 8; ++i) {
            float4 c4 = *(const float4*)(xrow + 4 * i);
            b0 = fmaf(Wx[4*i+0], c4.x, b0);
            b1 = fmaf(Wx[4*i+1], c4.y, b1);
            b2 = fmaf(Wx[4*i+2], c4.z, b2);
            b3 = fmaf(Wx[4*i+3], c4.w, b3);
        }
        float zx2 = (b0 + b1) + (b2 + b3);
        zx2 += dpp_mov<0xB1>(zx2);
        zx2 += dpp_mov<0x4E>(zx2);
        if ((ln & 3) == 0) zxbuf[0][8 * gz + qz] = zx2;
    }
    __syncthreads();

    const float* hsrc = &hbuf[16 * part8 + 4 * (part8 >> 1)];
    const size_t orow_step = (size_t)BB * HH;
    size_t orow = (size_t)bId * HH + tid;

    #pragma unroll 8
    for (int t = 0; t < TT; ++t) {
        const float zxs = zxbuf[t & 1][8 * wv + qub];
        const float4 h0 = ((const float4*)hsrc)[0];
        const float4 h1 = *(const float4*)(hsrc + 4);
        const float4 h2 = *(const float4*)(hsrc + 8);
        const float4 h3 = *(const float4*)(hsrc + 12);

        if (((t & 7) == 0) && wv == 3) {
            const int tch = (t >> 3) + 1;
            if (tch < TT / 8) {
                #pragma unroll
                for (int j = 0; j < 4; ++j) {
                    const int row = tch * 8 + 2 * j + xc_half;
                    xr[j] = *(const float4*)(p.x + ((size_t)row * BB + bId) * DD + xc_col);
                }
            }
        }

        float a0 = Wh[0] * h0.x, a1 = Wh[1] * h0.y, a2 = Wh[2] * h0.z, a3 = Wh[3] * h0.w;
        a0 = fmaf(Wh[4],  h1.x, a0); a1 = fmaf(Wh[5],  h1.y, a1);
        a2 = fmaf(Wh[6],  h1.z, a2); a3 = fmaf(Wh[7],  h1.w, a3);
        a0 = fmaf(Wh[8],  h2.x, a0); a1 = fmaf(Wh[9],  h2.y, a1);
        a2 = fmaf(Wh[10], h2.z, a2); a3 = fmaf(Wh[11], h2.w, a3);
        a0 = fmaf(Wh[12], h3.x, a0); a1 = fmaf(Wh[13], h3.y, a1);
        a2 = fmaf(Wh[14], h3.z, a2); a3 = fmaf(Wh[15], h3.w, a3);
        float acc = (a0 + a1) + (a2 + a3);
        acc += dpp_mov<0xB1>(acc);
        acc += dpp_mov<0x4E>(acc);
        acc += dpp_mov<0x141>(acc);
        acc += zxs + breg;

        const float cv = __cosf(acc);
        float v = cv;
        v *= dpp_mul1<0x118, 0xF>(v);
        v *= dpp_mul1<0x142, 0xA>(v);
        v *= dpp_mul1<0x143, 0xC>(v);
        float u = (ln < 8) ? 1.f : cv;
        u *= dpp_mul1<0x118, 0xF>(u);
        u *= dpp_mul1<0x142, 0xA>(u);
        u *= dpp_mul1<0x143, 0xC>(u);
        const float q0 = RDLANE(u, 63);
        const float q1 = RDLANE(v, 8);
        const float q2 = RDLANE(v, 16);
        const float q3 = RDLANE(v, 24);
        const float q4 = RDLANE(v, 32);
        const float q5 = RDLANE(v, 40);
        const float q6 = RDLANE(v, 48);
        const float q7 = RDLANE(v, 56);

        float a01 = fmaf(Ua[1], q1, Ua[0] * q0);
        float b01 = fmaf(Ub[1], q1, Ub[0] * q0);
        float a23 = fmaf(Ua[3], q3, Ua[2] * q2);
        float b23 = fmaf(Ub[3], q3, Ub[2] * q2);
        float a45 = fmaf(Ua[5], q5, Ua[4] * q4);
        float b45 = fmaf(Ub[5], q5, Ub[4] * q4);
        float a67 = fmaf(Ua[7], q7, Ua[6] * q6);
        float b67 = fmaf(Ub[7], q7, Ub[6] * q6);
        float pa = ((a01 + a23) + (a45 + a67)) + cba;
        float pb = ((b01 + b23) + (b45 + b67)) + cbb;
        pre[wv * 128 + ln]      = pa;
        pre[wv * 128 + 64 + ln] = pb;

        bar_lds();

        if (tid < 128) {
            float p_f = (wv == 0) ? pa : pre[tid];
            float p_i = (wv == 1) ? pb : pre[128 + tid];
            float p_g = pre[256 + tid];
            float p_o = pre[384 + tid];
            float fg = rcp_f(1.f + exp2_f(p_f));
            float ig = rcp_f(1.f + exp2_f(p_i));
            float gg = fmaf(-2.f, rcp_f(1.f + exp2_f(p_g)), 1.f);
            float og = rcp_f(1.f + exp2_f(p_o));
            cst = fmaf(fg, cst, ig * gg);
            float tc = fmaf(-2.f, rcp_f(1.f + exp2_f(cst * 2.885390081777927f)), 1.f);
            float hn = og * tc;
            hn_last = hn;
            hbuf[tid + 4 * (tid >> 5)] = hn;
            p.out[orow] = hn;
            orow += orow_step;
        } else {
            if (wv == 3 && (t & 7) == 6) {
                const int tch = (t >> 3) + 1;
                if (tch < TT / 8) {
                    #pragma unroll
                    for (int j = 0; j < 4; ++j) {
                        const int row = 2 * j + xc_half;
                        *(float4*)&xbuf[tch & 1][row][xc_slot] = xr[j];
                    }
                }
            }
            if (t < TT - 1) {
                const int tn = t + 1;
                const float* xrow = &xbuf[(tn >> 3) & 1][tn & 7][36 * pz];
                float4 c[8];
                #pragma unroll
                for (int i = 0; i < 8; ++i) c[i] = *(const float4*)(xrow + 4 * i);
                float b0 = Wx[0] * c[0].x, b1 = Wx[1] * c[0].y;
                float b2 = Wx[2] * c[0].z, b3 = Wx[3] * c[0].w;
                #pragma unroll
                for (int i = 1; i < 8; ++i) {
                    b0 = fmaf(Wx[4*i+0], c[i].x, b0);
                    b1 = fmaf(Wx[4*i+1], c[i].y, b1);
                    b2 = fmaf(Wx[4*i+2], c[i].z, b2);
                    b3 = fmaf(Wx[4*i+3], c[i].w, b3);
                }
                float zx2 = (b0 + b1) + (b2 + b3);
                zx2 += dpp_mov<0xB1>(zx2);
                zx2 += dpp_mov<0x4E>(zx2);
                if ((ln & 3) == 0) zxbuf[tn & 1][8 * gz + qz] = zx2;
            }
        }
        bar_lds();
    }

    if (tid < 128) {
        p.out[(size_t)TT * BB * HH + (size_t)bId * HH + tid] = hn_last;
        p.out[(size_t)TT * BB * HH + (size_t)BB * HH + (size_t)bId * HH + tid] = cst;
    }
}

extern "C" void kernel_launch(void* const* d_in, const int* in_sizes, int n_in,
                              void* d_out, int out_size, void* d_ws, size_t ws_size,
                              hipStream_t stream) {
    (void)in_sizes; (void)n_in; (void)out_size;
    Params p;
    p.x = (const float*)d_in[0];
    for (int g = 0; g < 4; ++g) {
        p.W[g]  = (const float*)d_in[1 + 5 * g + 0];
        p.b[g]  = (const float*)d_in[1 + 5 * g + 1];
        p.th[g] = (const float*)d_in[1 + 5 * g + 2];
        p.U[g]  = (const float*)d_in[1 + 5 * g + 3];
        p.cb[g] = (const float*)d_in[1 + 5 * g + 4];
    }
    p.out = (float*)d_out;

    const size_t ZXB = (size_t)TT * BB * 32 * sizeof(float);   // 16.8 MB
    if (d_ws != nullptr && ws_size >= ZXB) {
        GParams g;
        g.x = p.x;
        for (int i = 0; i < 4; ++i) g.W[i] = p.W[i];
        g.zx = (float*)d_ws;
        p.zx = (const float*)d_ws;
        // T*B/32 waves / 4 per block = 1024 blocks
        hipLaunchKernelGGL(zxgemm, dim3(TT * BB / 32 / 4), dim3(256), 0, stream, g);
        hipLaunchKernelGGL(qlstm, dim3(BB), dim3(256), 0, stream, p);
    } else {
        p.zx = nullptr;
        hipLaunchKernelGGL(qlstm_fb, dim3(BB), dim3(256), 0, stream, p);
    }
}

// Round 4
// 421.600 us; speedup vs baseline: 1.1395x; 1.1395x over previous
//
#include <hip/hip_runtime.h>

#define TT 512
#define BB 256
#define DD 128
#define HH 128
#define QQ 8

struct Params {
    const float* x;
    const float* W[4];
    const float* b[4];
    const float* th[4];
    const float* U[4];
    const float* cb[4];
    float* out;
};

__device__ __forceinline__ float rcp_f(float x)  { return __builtin_amdgcn_rcpf(x); }
__device__ __forceinline__ float exp2_f(float x) { return __builtin_amdgcn_exp2f(x); }

// DPP move (old=0, bound_ctrl=on): for sum butterflies where all sources valid.
template<int CTRL>
__device__ __forceinline__ float dpp_mov(float x) {
    int r = __builtin_amdgcn_update_dpp(0, __float_as_int(x), CTRL, 0xF, 0xF, true);
    return __int_as_float(r);
}
// DPP with multiplicative-identity fallback: lanes w/o valid source keep old=1.0f.
template<int CTRL>
__device__ __forceinline__ float dpp_mul1(float x) {
    int r = __builtin_amdgcn_update_dpp(0x3f800000 /*1.0f*/, __float_as_int(x),
                                        CTRL, 0xF, 0xF, false);
    return __int_as_float(r);
}
#define RDLANE(v, l) __int_as_float(__builtin_amdgcn_readlane(__float_as_int(v), (l)))

// Uexp 8-term dot, tree form (order matches R2 for numeric stability)
#define GDOT(U8, CB, P0,P1,P2,P3,P4,P5,P6,P7) \
    (((fmaf((U8)[1],(P1),(U8)[0]*(P0)) + fmaf((U8)[3],(P3),(U8)[2]*(P2))) + \
      (fmaf((U8)[5],(P5),(U8)[4]*(P4)) + fmaf((U8)[7],(P7),(U8)[6]*(P6)))) + (CB))

// One block per batch element. Wave-specialized, launch-overhead-minimal design:
//   waves 1-3 (producers): compute ALL zx[t][g*8+q] = W[g][q][0:128].x[t][b]
//     into a 64KB LDS ring, t strided by 3. One __syncthreads after t<64 is
//     ready; thereafter producers (~55cy/t aggregate) stay >=16x ahead of the
//     consumer (>=700cy/t) -- no further sync needed. Producers exit early.
//   wave 0 (consumer): the whole recurrence, ZERO barriers per step.
//     lane = (gate=ln>>4, qubit=(ln>>1)&7, half=ln&1) for the zh dot;
//     DPP pair-reduce -> cos -> 16-lane row_shr DPP product scan ->
//     32 readlane broadcasts of P(g,q) -> per-lane Uexp+E for h=2ln,2ln+1 ->
//     h writeback via intra-wave LDS RTT (in-order pipe, no barrier).
// LDS pad for hbuf: slot(k) = k + 4*(k>>5).
__global__ __launch_bounds__(256, 1) void qlstm(Params p) {
    __shared__ __align__(16) float zxr[TT][32];   // 64KB: full zx for this b
    __shared__ __align__(16) float hbuf[144];     // h_{t-1}, padded

    const int tid = threadIdx.x;
    const int bId = blockIdx.x;
    const int ln  = tid & 63;
    const int wv  = tid >> 6;

    // ---- producer state (lives across the barrier on producer waves) ----
    int tp = wv - 1;
    float4 wx[16];
    const float* xb = nullptr;
    int pgq = 0, phalf = 0;

#define PRODUCE(tt) { \
        const float* xp = xb + (size_t)(tt) * (BB * DD); \
        float4 c0 = *(const float4*)(xp); \
        float b0 = wx[0].x * c0.x, b1 = wx[0].y * c0.y; \
        float b2 = wx[0].z * c0.z, b3 = wx[0].w * c0.w; \
        _Pragma("unroll") \
        for (int j = 1; j < 16; ++j) { \
            float4 c = *(const float4*)(xp + 4 * j); \
            b0 = fmaf(wx[j].x, c.x, b0); b1 = fmaf(wx[j].y, c.y, b1); \
            b2 = fmaf(wx[j].z, c.z, b2); b3 = fmaf(wx[j].w, c.w, b3); } \
        float s = (b0 + b1) + (b2 + b3); \
        s += dpp_mov<0xB1>(s); \
        if (phalf == 0) zxr[tt][pgq] = s; }

    if (wv != 0) {
        pgq   = ln >> 1;             // 0..31: gate = pgq>>3, qubit = pgq&7
        phalf = ln & 1;              // 64-float x-half
        const float* Wp = p.W[pgq >> 3] + (pgq & 7) * (DD + HH) + phalf * 64;
        #pragma unroll
        for (int j = 0; j < 16; ++j) wx[j] = *(const float4*)(Wp + 4 * j);
        xb = p.x + (size_t)bId * DD + phalf * 64;
        for (; tp < 64; tp += 3) PRODUCE(tp)
    }

    __syncthreads();   // zxr[0..63] ready; hereafter timing margin >=16x

    if (wv != 0) {     // finish the remaining t, then retire
        for (; tp < TT; tp += 3) PRODUCE(tp)
        return;
    }

    // ================= wave 0: the recurrence =================
    const int g    = ln >> 4;        // gate
    const int rr   = ln & 15;
    const int q    = rr >> 1;        // qubit
    const int half = rr & 1;         // h-half of the zh dot

    float4 wh[16];
    {
        const float* Wg = p.W[g] + q * (DD + HH) + DD + half * 64;
        #pragma unroll
        for (int j = 0; j < 16; ++j) wh[j] = *(const float4*)(Wg + 4 * j);
    }
    const float breg = p.b[g][q] + p.th[g][q];

    // U', cb' pre-scaled per gate: f,i,o -> -log2e (sigmoid via exp2);
    // g -> +2log2e (tanh via exp2). Lane owns h0=2ln, h1=2ln+1.
    float Ua[4][8], Ub[4][8], cba[4], cbb[4];
    #pragma unroll
    for (int gg2 = 0; gg2 < 4; ++gg2) {
        const float e = (gg2 == 2) ? 2.885390081777927f : -1.442695040888963f;
        const float* Up = p.U[gg2] + (size_t)(2 * ln) * QQ;
        #pragma unroll
        for (int j = 0; j < 8; ++j) Ua[gg2][j] = Up[j] * e;
        #pragma unroll
        for (int j = 0; j < 8; ++j) Ub[gg2][j] = Up[QQ + j] * e;
        cba[gg2] = p.cb[gg2][2 * ln] * e;
        cbb[gg2] = p.cb[gg2][2 * ln + 1] * e;
    }

    const int ws = 2 * ln + 4 * ((2 * ln) >> 5);   // padded b64 write slot
    float2 hw = make_float2(0.f, 0.f);
    *(float2*)&hbuf[ws] = hw;                      // h = 0 (own-wave, in-order)
    float cst0 = 0.f, cst1 = 0.f;

    const float* hp = &hbuf[half * 72];            // padded base of h-half
    float* outp = p.out + (size_t)bId * HH + 2 * ln;
    const size_t ostep = (size_t)BB * HH;

    for (int t = 0; t < TT; ++t) {
        // zx read first (independent), then streamed h reads (b128, broadcast)
        const float zxv = zxr[t][8 * g + q];
        float a0, a1, a2, a3;
        {
            float4 c = *(const float4*)(hp);
            a0 = wh[0].x * c.x; a1 = wh[0].y * c.y;
            a2 = wh[0].z * c.z; a3 = wh[0].w * c.w;
        }
        #pragma unroll
        for (int i = 1; i < 8; ++i) {
            float4 c = *(const float4*)(hp + 4 * i);
            a0 = fmaf(wh[i].x, c.x, a0); a1 = fmaf(wh[i].y, c.y, a1);
            a2 = fmaf(wh[i].z, c.z, a2); a3 = fmaf(wh[i].w, c.w, a3);
        }
        #pragma unroll
        for (int i = 8; i < 16; ++i) {
            float4 c = *(const float4*)(hp + 4 * i + 4);   // skip pad at +32
            a0 = fmaf(wh[i].x, c.x, a0); a1 = fmaf(wh[i].y, c.y, a1);
            a2 = fmaf(wh[i].z, c.z, a2); a3 = fmaf(wh[i].w, c.w, a3);
        }
        float acc = (a0 + a1) + (a2 + a3);
        acc += dpp_mov<0xB1>(acc);        // half0+half1 -> full zh on both lanes
        acc += zxv + breg;

        // qgate: cos, then inclusive product scan over q within the 16-lane row
        const float cv = __cosf(acc);
        float v = cv;                     // cp[q] scan (pairs duplicated)
        v *= dpp_mul1<0x112>(v);          // row_shr:2  (1 qubit)
        v *= dpp_mul1<0x114>(v);          // row_shr:4  (2 qubits)
        v *= dpp_mul1<0x118>(v);          // row_shr:8  (4 qubits)
        float u = (rr < 2) ? 1.f : cv;    // scan excluding qubit 0
        u *= dpp_mul1<0x112>(u);
        u *= dpp_mul1<0x114>(u);
        u *= dpp_mul1<0x118>(u);

        // broadcast all 32 P(g,q): q0 from u@row-end, q>=1 from v@lane 16g+2q
        const float P00 = RDLANE(u, 15), P01 = RDLANE(v, 2),  P02 = RDLANE(v, 4),
                    P03 = RDLANE(v, 6),  P04 = RDLANE(v, 8),  P05 = RDLANE(v, 10),
                    P06 = RDLANE(v, 12), P07 = RDLANE(v, 14);
        const float P10 = RDLANE(u, 31), P11 = RDLANE(v, 18), P12 = RDLANE(v, 20),
                    P13 = RDLANE(v, 22), P14 = RDLANE(v, 24), P15 = RDLANE(v, 26),
                    P16 = RDLANE(v, 28), P17 = RDLANE(v, 30);
        const float P20 = RDLANE(u, 47), P21 = RDLANE(v, 34), P22 = RDLANE(v, 36),
                    P23 = RDLANE(v, 38), P24 = RDLANE(v, 40), P25 = RDLANE(v, 42),
                    P26 = RDLANE(v, 44), P27 = RDLANE(v, 46);
        const float P30 = RDLANE(u, 63), P31 = RDLANE(v, 50), P32 = RDLANE(v, 52),
                    P33 = RDLANE(v, 54), P34 = RDLANE(v, 56), P35 = RDLANE(v, 58),
                    P36 = RDLANE(v, 60), P37 = RDLANE(v, 62);

        // Uexp (scaled) for h0, h1
        const float pf0 = GDOT(Ua[0], cba[0], P00,P01,P02,P03,P04,P05,P06,P07);
        const float pi0 = GDOT(Ua[1], cba[1], P10,P11,P12,P13,P14,P15,P16,P17);
        const float pg0 = GDOT(Ua[2], cba[2], P20,P21,P22,P23,P24,P25,P26,P27);
        const float po0 = GDOT(Ua[3], cba[3], P30,P31,P32,P33,P34,P35,P36,P37);
        const float pf1 = GDOT(Ub[0], cbb[0], P00,P01,P02,P03,P04,P05,P06,P07);
        const float pi1 = GDOT(Ub[1], cbb[1], P10,P11,P12,P13,P14,P15,P16,P17);
        const float pg1 = GDOT(Ub[2], cbb[2], P20,P21,P22,P23,P24,P25,P26,P27);
        const float po1 = GDOT(Ub[3], cbb[3], P30,P31,P32,P33,P34,P35,P36,P37);

        // E for h0
        float fg0 = rcp_f(1.f + exp2_f(pf0));
        float ig0 = rcp_f(1.f + exp2_f(pi0));
        float gg0 = fmaf(-2.f, rcp_f(1.f + exp2_f(pg0)), 1.f);
        float og0 = rcp_f(1.f + exp2_f(po0));
        cst0 = fmaf(fg0, cst0, ig0 * gg0);
        float tc0 = fmaf(-2.f, rcp_f(1.f + exp2_f(cst0 * 2.885390081777927f)), 1.f);
        hw.x = og0 * tc0;
        // E for h1
        float fg1 = rcp_f(1.f + exp2_f(pf1));
        float ig1 = rcp_f(1.f + exp2_f(pi1));
        float gg1 = fmaf(-2.f, rcp_f(1.f + exp2_f(pg1)), 1.f);
        float og1 = rcp_f(1.f + exp2_f(po1));
        cst1 = fmaf(fg1, cst1, ig1 * gg1);
        float tc1 = fmaf(-2.f, rcp_f(1.f + exp2_f(cst1 * 2.885390081777927f)), 1.f);
        hw.y = og1 * tc1;

        *(float2*)&hbuf[ws] = hw;     // intra-wave: next step's reads see it
        *(float2*)outp = hw;          // issue-only, coalesced 512B/wave
        outp += ostep;
    }

    // ---- tail: hx, cx ----
    float* tl = p.out + (size_t)TT * BB * HH + (size_t)bId * HH + 2 * ln;
    *(float2*)tl = hw;
    *(float2*)(tl + (size_t)BB * HH) = make_float2(cst0, cst1);
#undef PRODUCE
}

extern "C" void kernel_launch(void* const* d_in, const int* in_sizes, int n_in,
                              void* d_out, int out_size, void* d_ws, size_t ws_size,
                              hipStream_t stream) {
    (void)in_sizes; (void)n_in; (void)out_size; (void)d_ws; (void)ws_size;
    Params p;
    p.x = (const float*)d_in[0];
    for (int g = 0; g < 4; ++g) {
        p.W[g]  = (const float*)d_in[1 + 5 * g + 0];
        p.b[g]  = (const float*)d_in[1 + 5 * g + 1];
        p.th[g] = (const float*)d_in[1 + 5 * g + 2];
        p.U[g]  = (const float*)d_in[1 + 5 * g + 3];
        p.cb[g] = (const float*)d_in[1 + 5 * g + 4];
    }
    p.out = (float*)d_out;
    hipLaunchKernelGGL(qlstm, dim3(BB), dim3(256), 0, stream, p);
}